// Round 3
// baseline (5820.855 us; speedup 1.0000x reference)
//
#include <hip/hip_runtime.h>

// VQ-VAE VectorQuantizer: z_e [32,1024,256] f32, codebook [8192,256] f32.
// Outputs (flat f32): z_q_st [8388608], vq_loss [1], codes_idx-as-float [32768].
//
// SEMANTICS (locked in round 1): the harness ref is a faithful float32 numpy
// transliteration. dist = z_sq - 2*ze + e_sq has magnitude ~256 (z_sq), so
// fp32 dist is quantized to ulp(~256) ~ 1.5e-5 while score spread is ~2e-3:
// ~180/32768 rows have near-ties within one ulp, resolved by quantized
// equality + FIRST INDEX. We must therefore replicate:
//   - z_sq, e_sq: numpy pairwise fp32 sum (exact order), squares fp32-rounded
//   - ze: exact (fp64) dot rounded to fp32 (~5e-10 from BLAS, << ulp grid)
//   - dist = (z_sq - 2f*ze) + e_sq elementwise fp32, argmin first-index

#define NUM_CODES 8192
#define DIM 256
#define DIM4 64            // DIM / 4 (float4 units)
#define ROWS_PER_BLOCK 16
#define TILE_K 64
#define TOTAL_ROWS 32768
#define OUT_LOSS_OFF 8388608
#define OUT_IDX_OFF 8388609
#define LOSS_SCALE (1.25 / 8388608.0)   // (1 + BETA) / (B*N*D)

// fp32-rounded square; asm barrier blocks -ffp-contract=fast from fusing the
// square into the following add (numpy computes x*x as a separate fp32 array).
__device__ __forceinline__ float sq32(float v) {
    float s = v * v;
    asm("" : "+v"(s));
    return s;
}

// numpy pairwise sum of 256 fp32 squares, lane-parallel (16 lanes per row):
// lane = r*16 + h*8 + j; acc_j(half h) = x[h*128+j] + x[h*128+8+j] + ...
// (16 sequential adds), tree ((r0+r1)+(r2+r3))+((r4+r5)+(r6+r7)), halves last.
// IEEE add is commutative, so shfl_xor pairing reproduces numpy's exact bits.
// Lanes with (l&15)==0 end up holding the row sum.
__device__ __forceinline__ float pairwise256_sq(const float* __restrict__ base,
                                                int l) {
    const int h = (l >> 3) & 1, j = l & 7;
    const float* p = base + h * 128 + j;
    float acc = sq32(p[0]);
    #pragma unroll
    for (int m = 1; m < 16; ++m) acc += sq32(p[m * 8]);
    acc += __shfl_xor(acc, 1);
    acc += __shfl_xor(acc, 2);
    acc += __shfl_xor(acc, 4);
    acc += __shfl_xor(acc, 8);
    return acc;
}

// ------------------------------------------------- e_sq (np pairwise) ----
__global__ __launch_bounds__(64) void vq_esq_kernel(const float* __restrict__ cb,
                                                    float* __restrict__ esq) {
    const int l = threadIdx.x;
    const int r = l >> 4;
    const int code = (blockIdx.x << 2) + r;          // 4 codes per wave
    float s = pairwise256_sq(cb + (long)code * DIM, l);
    if ((l & 15) == 0) esq[code] = s;
}

// -------------------------------------------------------------- argmin ----
__global__ __launch_bounds__(256) void vq_argmin_kernel(
        const float* __restrict__ z, const float* __restrict__ cb,
        const float* __restrict__ esq, float* __restrict__ out,
        double* __restrict__ loss_acc) {
    __shared__ float4 zt[ROWS_PER_BLOCK * DIM4];   // 16 KB, linear
    __shared__ float4 ct[TILE_K * DIM4];           // 64 KB, XOR-swizzled

    const int tid = threadIdx.x;
    const int w = tid >> 6, l = tid & 63;          // wave, lane
    const long rowbase = (long)blockIdx.x * ROWS_PER_BLOCK;
    const float4* z4  = reinterpret_cast<const float4*>(z) + rowbase * DIM4;
    const float4* cb4 = reinterpret_cast<const float4*>(cb);

    // stage z rows (coalesced, 4 float4 per thread)
    #pragma unroll
    for (int i = 0; i < ROWS_PER_BLOCK * DIM4 / 256; ++i)
        zt[i * 256 + tid] = z4[i * 256 + tid];
    __syncthreads();

    // z_sq for this wave's 4 rows, numpy pairwise fp32 from the staged bits
    const float* zs = reinterpret_cast<const float*>(zt);
    const int rl = l >> 4;
    float accA = pairwise256_sq(zs + ((w << 2) + rl) * DIM, l);
    const float A0 = __shfl(accA, 0),  A1 = __shfl(accA, 16);
    const float A2 = __shfl(accA, 32), A3 = __shfl(accA, 48);

    float best0 = 3.4e38f, best1 = 3.4e38f, best2 = 3.4e38f, best3 = 3.4e38f;
    int bk0 = 0, bk1 = 0, bk2 = 0, bk3 = 0;

    for (int t = 0; t < NUM_CODES / TILE_K; ++t) {
        __syncthreads();
        // stage codebook tile; swizzle float4 slot: row kk, slot (l ^ kk)
        #pragma unroll
        for (int i = 0; i < TILE_K * DIM4 / 256; ++i) {
            const int kk = (i << 2) + w;
            ct[kk * DIM4 + (l ^ kk)] = cb4[(long)(t * TILE_K + kk) * DIM4 + l];
        }
        __syncthreads();

        // lane l owns code (t*TILE_K + l); wave w owns rows 4w..4w+3.
        // fp64 dot = exact; rounded to fp32 below (~BLAS within 5e-10).
        double a0 = 0.0, a1 = 0.0, a2 = 0.0, a3 = 0.0;
        const float4* zr = zt + (w << 2) * DIM4;
        for (int d = 0; d < DIM4; ++d) {
            float4 c  = ct[l * DIM4 + (d ^ l)];    // swizzled: bank-balanced
            float4 r0 = zr[d],            r1 = zr[DIM4 + d];
            float4 r2 = zr[2 * DIM4 + d], r3 = zr[3 * DIM4 + d];
            a0 += (double)c.x * r0.x + (double)c.y * r0.y + (double)c.z * r0.z + (double)c.w * r0.w;
            a1 += (double)c.x * r1.x + (double)c.y * r1.y + (double)c.z * r1.z + (double)c.w * r1.w;
            a2 += (double)c.x * r2.x + (double)c.y * r2.y + (double)c.z * r2.z + (double)c.w * r2.w;
            a3 += (double)c.x * r3.x + (double)c.y * r3.y + (double)c.z * r3.z + (double)c.w * r3.w;
        }
        const int k = t * TILE_K + l;
        const float e = esq[k];
        // np elementwise order: (z_sq - 2.0*ze) + e_sq, all fp32.
        const float s0 = (A0 - 2.0f * (float)a0) + e;
        const float s1 = (A1 - 2.0f * (float)a1) + e;
        const float s2 = (A2 - 2.0f * (float)a2) + e;
        const float s3 = (A3 - 2.0f * (float)a3) + e;
        if (s0 < best0) { best0 = s0; bk0 = k; }   // strict < keeps lowest k
        if (s1 < best1) { best1 = s1; bk1 = k; }
        if (s2 < best2) { best2 = s2; bk2 = k; }
        if (s3 < best3) { best3 = s3; bk3 = k; }
    }

    float bests[4] = {best0, best1, best2, best3};
    int   bks[4]   = {bk0, bk1, bk2, bk3};
    #pragma unroll
    for (int i = 0; i < 4; ++i) {
        float s = bests[i]; int k = bks[i];
        #pragma unroll
        for (int off = 32; off; off >>= 1) {       // butterfly: min, tie->lower k
            float sx = __shfl_xor(s, off);
            int   kx = __shfl_xor(k, off);
            if (sx < s || (sx == s && kx < k)) { s = sx; k = kx; }
        }
        const long row = rowbase + (w << 2) + i;
        if (l == 0) out[OUT_IDX_OFF + row] = (float)k;
        // z_q_st == z_q numerically; exact bit-copy of the codebook row
        float4 cq = cb4[(long)k * DIM4 + l];
        reinterpret_cast<float4*>(out)[row * DIM4 + l] = cq;
        // loss partial: sum (z_q - z_e)^2 in fp64
        float4 zz = zt[((w << 2) + i) * DIM4 + l];
        const double dx = (double)cq.x - zz.x, dy = (double)cq.y - zz.y;
        const double dz = (double)cq.z - zz.z, dw = (double)cq.w - zz.w;
        double ld = dx * dx + dy * dy + dz * dz + dw * dw;
        #pragma unroll
        for (int off = 32; off; off >>= 1) ld += __shfl_xor(ld, off);
        if (l == 0) atomicAdd(loss_acc, ld);
    }
}

// ------------------------------------------------------------ finalize ----
__global__ void vq_finalize_kernel(const double* __restrict__ loss_acc,
                                   float* __restrict__ out) {
    out[OUT_LOSS_OFF] = (float)(*loss_acc * LOSS_SCALE);
}

// -------------------------------------------------------------- launch ----
extern "C" void kernel_launch(void* const* d_in, const int* in_sizes, int n_in,
                              void* d_out, int out_size, void* d_ws, size_t ws_size,
                              hipStream_t stream) {
    const float* z  = (const float*)d_in[0];
    const float* cb = (const float*)d_in[1];
    float* out = (float*)d_out;
    double* loss_acc = (double*)d_ws;                    // 8 B at offset 0
    float* esq = (float*)((char*)d_ws + 1024);           // 32 KB, aligned

    hipMemsetAsync(d_ws, 0, 8, stream);                  // zero loss accumulator
    vq_esq_kernel<<<NUM_CODES / 4, 64, 0, stream>>>(cb, esq);
    vq_argmin_kernel<<<TOTAL_ROWS / ROWS_PER_BLOCK, 256, 0, stream>>>(
        z, cb, esq, out, loss_acc);
    vq_finalize_kernel<<<1, 1, 0, stream>>>(loss_acc, out);
}

// Round 4
// 5080.508 us; speedup vs baseline: 1.1457x; 1.1457x over previous
//
#include <hip/hip_runtime.h>

// VQ-VAE VectorQuantizer: z_e [32,1024,256] f32, codebook [8192,256] f32.
// Outputs (flat f32): z_q_st [8388608], vq_loss [1], codes_idx-as-float [32768].
//
// SEMANTICS (verified passing in round 3): ref is fp32 numpy.
//   dist = (z_sq - 2*ze) + e_sq, quantized fp32 at ulp(~256)~1.5e-5; argmin
//   resolves frequent quantized ties by FIRST INDEX. z_sq/e_sq = numpy
//   pairwise fp32; ze = exact (fp64) dot rounded fp32 (δ vs BLAS ~5e-10).
//
// THIS ROUND: two-phase. Phase 1 scans all 8192 codes per row in fp32 FMA
// (worst-case dot error γ_256·Σ|z·c| ≈ 8e-7 << MARGIN/2), tracking per-lane
// best-3 (score,idx). Phase 2 re-scores only candidates within MARGIN=1e-4
// of the approx min (expected ~1.2/row) with the exact fp64 + ref-quantized
// formula, picking min over packed (fp32bits<<32 | idx) -> exact first-index
// argmin semantics, identical to the round-3 passing kernel.

#define NUM_CODES 8192
#define DIM 256
#define DIM4 64            // DIM / 4 (float4 units)
#define ROWS_PER_BLOCK 32
#define TILE_K 32
#define TOTAL_ROWS 32768
#define OUT_LOSS_OFF 8388608
#define OUT_IDX_OFF 8388609
#define LOSS_SCALE (1.25 / 8388608.0)   // (1 + BETA) / (B*N*D)
#define MARGIN 1e-4f

// fp32-rounded square; blocks contraction into the following add.
__device__ __forceinline__ float sq32(float v) {
    float s = v * v;
    asm("" : "+v"(s));
    return s;
}

// numpy pairwise sum of 256 fp32 squares, 16 lanes per row (verified r3).
__device__ __forceinline__ float pairwise256_sq(const float* __restrict__ base,
                                                int l) {
    const int h = (l >> 3) & 1, j = l & 7;
    const float* p = base + h * 128 + j;
    float acc = sq32(p[0]);
    #pragma unroll
    for (int m = 1; m < 16; ++m) acc += sq32(p[m * 8]);
    acc += __shfl_xor(acc, 1);
    acc += __shfl_xor(acc, 2);
    acc += __shfl_xor(acc, 4);
    acc += __shfl_xor(acc, 8);
    return acc;
}

// ------------------------------------------------- e_sq (np pairwise) ----
__global__ __launch_bounds__(64) void vq_esq_kernel(const float* __restrict__ cb,
                                                    float* __restrict__ esq) {
    const int l = threadIdx.x;
    const int code = (blockIdx.x << 2) + (l >> 4);   // 4 codes per wave
    float s = pairwise256_sq(cb + (long)code * DIM, l);
    if ((l & 15) == 0) esq[code] = s;
}

// --------------------------------------------- scan + refine (fused) ----
__global__ __launch_bounds__(256) void vq_scan_kernel(
        const float* __restrict__ z, const float* __restrict__ cb,
        const float* __restrict__ esq, float* __restrict__ out,
        double* __restrict__ loss_acc) {
    __shared__ float4 zt[ROWS_PER_BLOCK * DIM4];   // 32 KB fp32 z rows
    __shared__ float4 ct[TILE_K * DIM4];           // 32 KB cb tile, XOR-swizzled
    __shared__ float Arow[ROWS_PER_BLOCK];         // z_sq per row

    const int tid = threadIdx.x;
    const int w = tid >> 6, l = tid & 63;
    const int h = l >> 5, lc = l & 31;             // half, code-slot
    const int rowg = w * 8 + h * 4;                // my 4 rows' base (in block)
    const long rowbase = (long)blockIdx.x * ROWS_PER_BLOCK;
    const float4* z4  = reinterpret_cast<const float4*>(z) + rowbase * DIM4;
    const float4* cb4 = reinterpret_cast<const float4*>(cb);
    float4* out4 = reinterpret_cast<float4*>(out);

    // ---- stage z (fp32) + tile 0 of cb (reg), compute A ----
    float4 zreg[8], nxt[8];
    #pragma unroll
    for (int i = 0; i < 8; ++i) zreg[i] = z4[i * 256 + tid];
    #pragma unroll
    for (int i = 0; i < 8; ++i) nxt[i] = cb4[i * 256 + tid];
    #pragma unroll
    for (int i = 0; i < 8; ++i) zt[i * 256 + tid] = zreg[i];
    __syncthreads();
    const float* zs = reinterpret_cast<const float*>(zt);
    {
        const int r0 = w * 8 + (l >> 4);
        float a = pairwise256_sq(zs + r0 * DIM, l);
        if ((l & 15) == 0) Arow[r0] = a;
        a = pairwise256_sq(zs + (r0 + 4) * DIM, l);
        if ((l & 15) == 0) Arow[r0 + 4] = a;
    }
    #pragma unroll
    for (int i = 0; i < 8; ++i) {                  // tile 0 -> LDS (swizzled)
        const int kk = i * 4 + w;                  // flat>>6; d4 = l
        ct[kk * DIM4 + (l ^ kk)] = nxt[i];
    }
    __syncthreads();

    const float A0 = Arow[rowg], A1 = Arow[rowg + 1];
    const float A2 = Arow[rowg + 2], A3 = Arow[rowg + 3];

    // per-lane best-3 per row (strict < keeps earliest = lowest k)
    float b1[4], b2[4], b3[4];
    int   k1[4], k2[4], k3[4];
    #pragma unroll
    for (int i = 0; i < 4; ++i) {
        b1[i] = b2[i] = b3[i] = 3.4e38f;
        k1[i] = k2[i] = k3[i] = 0;
    }

    const float4* zr  = zt + rowg * DIM4;
    const float4* ctl = ct + lc * DIM4;

    for (int t = 0; t < NUM_CODES / TILE_K; ++t) {
        if (t < NUM_CODES / TILE_K - 1) {          // T14: issue next tile early
            #pragma unroll
            for (int i = 0; i < 8; ++i)
                nxt[i] = cb4[(t + 1) * (TILE_K * DIM4) + i * 256 + tid];
        }
        const int k = t * TILE_K + lc;
        const float e = esq[k];                    // hidden under d-loop

        float a0 = 0.f, a1 = 0.f, a2 = 0.f, a3 = 0.f;
        #pragma unroll 8
        for (int d = 0; d < DIM4; ++d) {
            float4 c  = ctl[d ^ lc];               // swizzled, bank-balanced
            float4 r0 = zr[d],            r1 = zr[DIM4 + d];     // broadcast
            float4 r2 = zr[2 * DIM4 + d], r3 = zr[3 * DIM4 + d];
            a0 = fmaf(c.x, r0.x, fmaf(c.y, r0.y, fmaf(c.z, r0.z, fmaf(c.w, r0.w, a0))));
            a1 = fmaf(c.x, r1.x, fmaf(c.y, r1.y, fmaf(c.z, r1.z, fmaf(c.w, r1.w, a1))));
            a2 = fmaf(c.x, r2.x, fmaf(c.y, r2.y, fmaf(c.z, r2.z, fmaf(c.w, r2.w, a2))));
            a3 = fmaf(c.x, r3.x, fmaf(c.y, r3.y, fmaf(c.z, r3.z, fmaf(c.w, r3.w, a3))));
        }
        const float s0 = (A0 - 2.0f * a0) + e;
        const float s1 = (A1 - 2.0f * a1) + e;
        const float s2 = (A2 - 2.0f * a2) + e;
        const float s3 = (A3 - 2.0f * a3) + e;
        #pragma unroll
        for (int i = 0; i < 4; ++i) {
            const float s = (i == 0) ? s0 : (i == 1) ? s1 : (i == 2) ? s2 : s3;
            if (s < b3[i]) {
                if (s < b1[i])      { b3[i]=b2[i];k3[i]=k2[i]; b2[i]=b1[i];k2[i]=k1[i]; b1[i]=s;k1[i]=k; }
                else if (s < b2[i]) { b3[i]=b2[i];k3[i]=k2[i]; b2[i]=s;k2[i]=k; }
                else                { b3[i]=s;k3[i]=k; }
            }
        }
        __syncthreads();                           // done reading ct
        if (t < NUM_CODES / TILE_K - 1) {
            #pragma unroll
            for (int i = 0; i < 8; ++i) {
                const int kk = i * 4 + w;
                ct[kk * DIM4 + (l ^ kk)] = nxt[i];
            }
        }
        __syncthreads();                           // ct ready
    }

    // ---- refine: exact fp64 re-score of candidates, 32-lane cooperative ----
    const unsigned long long gmask = 0xFFFFFFFFull << (h * 32);
    double lacc = 0.0;
    const float Ai_[4] = {A0, A1, A2, A3};
    #pragma unroll 1
    for (int i = 0; i < 4; ++i) {
        const int row = rowg + i;
        float m = b1[i];
        m = fminf(m, __shfl_xor(m, 1));
        m = fminf(m, __shfl_xor(m, 2));
        m = fminf(m, __shfl_xor(m, 4));
        m = fminf(m, __shfl_xor(m, 8));
        m = fminf(m, __shfl_xor(m, 16));           // min over my 32-group
        const float thr = m + MARGIN;
        unsigned long long B1 = __ballot(b1[i] <= thr) & gmask;
        unsigned long long B2 = __ballot(b2[i] <= thr) & gmask;
        unsigned long long B3 = __ballot(b3[i] <= thr) & gmask;
        unsigned long long wmin = ~0ull;
        const float4 za = zt[row * DIM4 + lc];
        const float4 zb = zt[row * DIM4 + lc + 32];
        const float Ai = Ai_[i];

        #pragma unroll 1
        for (int j = 0; j < 3; ++j) {
            unsigned long long B = (j == 0) ? B1 : (j == 1) ? B2 : B3;
            while (B) {
                const int src = __ffsll(B) - 1;  B &= B - 1;
                int kc;
                if (j == 0)      kc = __shfl(k1[i], src);
                else if (j == 1) kc = __shfl(k2[i], src);
                else             kc = __shfl(k3[i], src);
                const float4 ca = cb4[(long)kc * DIM4 + lc];
                const float4 cc = cb4[(long)kc * DIM4 + lc + 32];
                double dd = (double)ca.x * za.x + (double)ca.y * za.y
                          + (double)ca.z * za.z + (double)ca.w * za.w
                          + (double)cc.x * zb.x + (double)cc.y * zb.y
                          + (double)cc.z * zb.z + (double)cc.w * zb.w;
                dd += __shfl_xor(dd, 1);
                dd += __shfl_xor(dd, 2);
                dd += __shfl_xor(dd, 4);
                dd += __shfl_xor(dd, 8);
                dd += __shfl_xor(dd, 16);          // full 256-dim exact dot
                const float s = (Ai - 2.0f * (float)dd) + esq[kc];  // ref bits
                const unsigned long long p =
                    ((unsigned long long)__float_as_uint(s) << 32) | (unsigned)kc;
                wmin = p < wmin ? p : wmin;
            }
        }
        const int kw = (int)(wmin & 0xFFFFFFFFull);
        const long grow = rowbase + row;
        const float4 qa = cb4[(long)kw * DIM4 + lc];
        const float4 qb = cb4[(long)kw * DIM4 + lc + 32];
        // z_q_st = z_e + (z_q - z_e) in fp32 (mimic ref rounding)
        float4 oa, ob;
        oa.x = za.x + (qa.x - za.x); oa.y = za.y + (qa.y - za.y);
        oa.z = za.z + (qa.z - za.z); oa.w = za.w + (qa.w - za.w);
        ob.x = zb.x + (qb.x - zb.x); ob.y = zb.y + (qb.y - zb.y);
        ob.z = zb.z + (qb.z - zb.z); ob.w = zb.w + (qb.w - zb.w);
        out4[grow * DIM4 + lc] = oa;
        out4[grow * DIM4 + lc + 32] = ob;
        if (lc == 0) out[OUT_IDX_OFF + grow] = (float)kw;
        const double d0 = (double)qa.x - za.x, d1 = (double)qa.y - za.y;
        const double d2 = (double)qa.z - za.z, d3 = (double)qa.w - za.w;
        const double d4 = (double)qb.x - zb.x, d5 = (double)qb.y - zb.y;
        const double d6 = (double)qb.z - zb.z, d7 = (double)qb.w - zb.w;
        lacc += d0*d0 + d1*d1 + d2*d2 + d3*d3 + d4*d4 + d5*d5 + d6*d6 + d7*d7;
    }
    lacc += __shfl_xor(lacc, 1);
    lacc += __shfl_xor(lacc, 2);
    lacc += __shfl_xor(lacc, 4);
    lacc += __shfl_xor(lacc, 8);
    lacc += __shfl_xor(lacc, 16);
    if (lc == 0) atomicAdd(loss_acc, lacc);
}

// ------------------------------------------------------------ finalize ----
__global__ void vq_finalize_kernel(const double* __restrict__ loss_acc,
                                   float* __restrict__ out) {
    out[OUT_LOSS_OFF] = (float)(*loss_acc * LOSS_SCALE);
}

// -------------------------------------------------------------- launch ----
extern "C" void kernel_launch(void* const* d_in, const int* in_sizes, int n_in,
                              void* d_out, int out_size, void* d_ws, size_t ws_size,
                              hipStream_t stream) {
    const float* z  = (const float*)d_in[0];
    const float* cb = (const float*)d_in[1];
    float* out = (float*)d_out;
    double* loss_acc = (double*)d_ws;                    // 8 B at offset 0
    float* esq = (float*)((char*)d_ws + 1024);           // 32 KB, aligned

    hipMemsetAsync(d_ws, 0, 8, stream);                  // zero loss accumulator
    vq_esq_kernel<<<NUM_CODES / 4, 64, 0, stream>>>(cb, esq);
    vq_scan_kernel<<<TOTAL_ROWS / ROWS_PER_BLOCK, 256, 0, stream>>>(
        z, cb, esq, out, loss_acc);
    vq_finalize_kernel<<<1, 1, 0, stream>>>(loss_acc, out);
}

// Round 5
// 1013.611 us; speedup vs baseline: 5.7427x; 5.0123x over previous
//
#include <hip/hip_runtime.h>

// VQ-VAE VectorQuantizer: z_e [32,1024,256] f32, codebook [8192,256] f32.
// Outputs (flat f32): z_q_st [8388608], vq_loss [1], codes_idx-as-float [32768].
//
// Verified semantics (r3/r4 passing): ref = fp32 numpy; dist = (z_sq-2*ze)+e_sq
// quantized at ulp(~256)~1.5e-5, ties -> first index. Final scoring replicates
// that exactly (fp64 dot -> fp32, np-pairwise z_sq/e_sq).
//
// THIS ROUND: bf16 MFMA scan (relative score = dot only; e_sq spread 7e-8 is
// folded into the margin). Phase A: per-row max approx-dot. Phase B: re-scan,
// candidates with dot >= max - MARGIN (covers worst-case bf16 error 2*1.2e-4
// + quantization window 6.6e-5) get exact re-score + CAS-min((fp32bits,idx)).

#define NUM_CODES 8192
#define DIM 256
#define TOTAL_ROWS 32768
#define ROWS_PER_BLOCK 128
#define ROWS_PER_WAVE 32
#define TILE_K 32                       // codes per LDS chunk
#define NCHUNK (NUM_CODES / TILE_K)     // 256
#define OUT_LOSS_OFF 8388608
#define OUT_IDX_OFF 8388609
#define LOSS_SCALE (1.25 / 8388608.0)   // (1+BETA)/(B*N*D)
#define DOT_MARGIN 3.5e-4f

typedef __attribute__((ext_vector_type(8))) short bf16x8;
typedef __attribute__((ext_vector_type(4))) float f32x4;

__device__ __forceinline__ unsigned short f2bf(float f) {   // RNE fp32->bf16
    union { float f; unsigned u; } v; v.f = f;
    return (unsigned short)((v.u + 0x7FFF + ((v.u >> 16) & 1)) >> 16);
}

__device__ __forceinline__ float sq32(float v) {            // block contraction
    float s = v * v;
    asm("" : "+v"(s));
    return s;
}

// numpy pairwise sum of 256 fp32 squares, 16 lanes/row (verified r3/r4).
__device__ __forceinline__ float pairwise256_sq(const float* __restrict__ base,
                                                int l) {
    const int h = (l >> 3) & 1, j = l & 7;
    const float* p = base + h * 128 + j;
    float acc = sq32(p[0]);
    #pragma unroll
    for (int m = 1; m < 16; ++m) acc += sq32(p[m * 8]);
    acc += __shfl_xor(acc, 1);
    acc += __shfl_xor(acc, 2);
    acc += __shfl_xor(acc, 4);
    acc += __shfl_xor(acc, 8);
    return acc;
}

// ---------------------------------------------- row ||x||^2 (np pairwise) ----
__global__ __launch_bounds__(64) void rowsq_kernel(const float* __restrict__ x,
                                                   float* __restrict__ sq) {
    const int l = threadIdx.x;
    const long row = ((long)blockIdx.x << 2) + (l >> 4);   // 4 rows per wave
    float s = pairwise256_sq(x + row * DIM, l);
    if ((l & 15) == 0) sq[row] = s;
}

// ------------------------------------------------------- fp32 -> bf16 ----
__global__ __launch_bounds__(256) void cvt_bf16_kernel(
        const float* __restrict__ x, unsigned short* __restrict__ o) {
    const long i = ((long)blockIdx.x * 256 + threadIdx.x) * 8;
    float4 a = *(const float4*)(x + i);
    float4 b = *(const float4*)(x + i + 4);
    union { unsigned short us[8]; uint4 v; } r;
    r.us[0] = f2bf(a.x); r.us[1] = f2bf(a.y); r.us[2] = f2bf(a.z); r.us[3] = f2bf(a.w);
    r.us[4] = f2bf(b.x); r.us[5] = f2bf(b.y); r.us[6] = f2bf(b.z); r.us[7] = f2bf(b.w);
    *(uint4*)(o + i) = r.v;
}

// ------------------------------------------------ MFMA scan + refine ----
__global__ __launch_bounds__(256, 1) void vq_scan_kernel(
        const float* __restrict__ z, const float* __restrict__ cb,
        const unsigned short* __restrict__ cb_bf,
        const float* __restrict__ esq, const float* __restrict__ zsq,
        float* __restrict__ out, double* __restrict__ loss_acc) {
    __shared__ bf16x8 ct[2][TILE_K * 32];            // 2 x 16 KB, XOR-swizzled
    __shared__ unsigned long long winner[ROWS_PER_BLOCK];

    const int tid = threadIdx.x;
    const int w = tid >> 6, l = tid & 63;
    const int cl = l & 15, g = l >> 4;               // frag col-lane, k-group
    const long rowbase = (long)blockIdx.x * ROWS_PER_BLOCK;
    const int wrowL = w * ROWS_PER_WAVE;

    if (tid < ROWS_PER_BLOCK) winner[tid] = ~0ull;

    // ---- A-frags: wave's 32 z rows (2 M-tiles), whole K=256, in regs ----
    bf16x8 af[2][8];
    #pragma unroll
    for (int t = 0; t < 2; ++t) {
        const long r = rowbase + wrowL + t * 16 + cl;
        #pragma unroll
        for (int ks = 0; ks < 8; ++ks) {
            const float* p = z + r * DIM + ks * 32 + g * 8;
            float4 a = *(const float4*)p, b = *(const float4*)(p + 4);
            bf16x8 v;
            v[0] = f2bf(a.x); v[1] = f2bf(a.y); v[2] = f2bf(a.z); v[3] = f2bf(a.w);
            v[4] = f2bf(b.x); v[5] = f2bf(b.y); v[6] = f2bf(b.z); v[7] = f2bf(b.w);
            af[t][ks] = v;
        }
    }

    uint4 sreg[4];
    #define STAGE_LOAD(ch) { \
        _Pragma("unroll") \
        for (int i_ = 0; i_ < 4; ++i_) { \
            const int f_ = i_ * 256 + tid; \
            sreg[i_] = *(const uint4*)(cb_bf + \
                ((long)(ch) * TILE_K + (f_ >> 5)) * DIM + (f_ & 31) * 8); \
        } }
    #define STAGE_WRITE(b_) { \
        _Pragma("unroll") \
        for (int i_ = 0; i_ < 4; ++i_) { \
            const int f_ = i_ * 256 + tid; \
            const int c_ = f_ >> 5, s_ = f_ & 31; \
            *(uint4*)&ct[b_][c_ * 32 + (s_ ^ (c_ & 7))] = sreg[i_]; \
        } }

    const int x7 = cl & 7;

    // =================== PHASE A: per-row max approx dot ===================
    float bmax[2][4];
    #pragma unroll
    for (int t = 0; t < 2; ++t)
        #pragma unroll
        for (int r = 0; r < 4; ++r) bmax[t][r] = -3.4e38f;

    STAGE_LOAD(0); STAGE_WRITE(0); __syncthreads();
    int buf = 0;
    for (int ch = 0; ch < NCHUNK; ++ch) {
        if (ch + 1 < NCHUNK) STAGE_LOAD(ch + 1);
        f32x4 acc[2][2];
        #pragma unroll
        for (int t = 0; t < 2; ++t)
            #pragma unroll
            for (int n = 0; n < 2; ++n) acc[t][n] = (f32x4){0.f, 0.f, 0.f, 0.f};
        #pragma unroll
        for (int ks = 0; ks < 8; ++ks) {
            #pragma unroll
            for (int nt = 0; nt < 2; ++nt) {
                bf16x8 b = ct[buf][nt * 512 + cl * 32 + ((((ks << 2) + g)) ^ x7)];
                acc[0][nt] = __builtin_amdgcn_mfma_f32_16x16x32_bf16(
                    af[0][ks], b, acc[0][nt], 0, 0, 0);
                acc[1][nt] = __builtin_amdgcn_mfma_f32_16x16x32_bf16(
                    af[1][ks], b, acc[1][nt], 0, 0, 0);
            }
        }
        #pragma unroll
        for (int t = 0; t < 2; ++t)
            #pragma unroll
            for (int r = 0; r < 4; ++r)
                bmax[t][r] = fmaxf(bmax[t][r], fmaxf(acc[t][0][r], acc[t][1][r]));
        __syncthreads();
        if (ch + 1 < NCHUNK) STAGE_WRITE(buf ^ 1);
        __syncthreads();
        buf ^= 1;
    }

    // reduce max across the 16 lanes sharing the same rows (same g)
    float thr[2][4];
    #pragma unroll
    for (int t = 0; t < 2; ++t)
        #pragma unroll
        for (int r = 0; r < 4; ++r) {
            float m = bmax[t][r];
            m = fmaxf(m, __shfl_xor(m, 1));
            m = fmaxf(m, __shfl_xor(m, 2));
            m = fmaxf(m, __shfl_xor(m, 4));
            m = fmaxf(m, __shfl_xor(m, 8));
            thr[t][r] = m - DOT_MARGIN;
        }

    // =================== PHASE B: candidates + exact refine =================
    STAGE_LOAD(0); STAGE_WRITE(0); __syncthreads();
    buf = 0;
    for (int ch = 0; ch < NCHUNK; ++ch) {
        if (ch + 1 < NCHUNK) STAGE_LOAD(ch + 1);
        f32x4 acc[2][2];
        #pragma unroll
        for (int t = 0; t < 2; ++t)
            #pragma unroll
            for (int n = 0; n < 2; ++n) acc[t][n] = (f32x4){0.f, 0.f, 0.f, 0.f};
        #pragma unroll
        for (int ks = 0; ks < 8; ++ks) {
            #pragma unroll
            for (int nt = 0; nt < 2; ++nt) {
                bf16x8 b = ct[buf][nt * 512 + cl * 32 + ((((ks << 2) + g)) ^ x7)];
                acc[0][nt] = __builtin_amdgcn_mfma_f32_16x16x32_bf16(
                    af[0][ks], b, acc[0][nt], 0, 0, 0);
                acc[1][nt] = __builtin_amdgcn_mfma_f32_16x16x32_bf16(
                    af[1][ks], b, acc[1][nt], 0, 0, 0);
            }
        }
        unsigned msk = 0;
        #pragma unroll
        for (int t = 0; t < 2; ++t)
            #pragma unroll
            for (int nt = 0; nt < 2; ++nt)
                #pragma unroll
                for (int r = 0; r < 4; ++r)
                    if (acc[t][nt][r] >= thr[t][r])
                        msk |= 1u << (t * 8 + nt * 4 + r);
        if (__any(msk != 0)) {
            unsigned long long act = __ballot(msk != 0);
            while (act) {
                const int src = __ffsll((unsigned long long)act) - 1;
                const unsigned m2 = __shfl(msk, src);
                const int bit = __ffs(m2) - 1;
                const int bt = bit >> 3, bnt = (bit >> 2) & 1, br = bit & 3;
                const int code = ch * TILE_K + bnt * 16 + (src & 15);
                const int rowL = wrowL + bt * 16 + ((src >> 4) & 3) * 4 + br;
                const long grow = rowbase + rowL;
                // exact fp64 dot, 64-lane cooperative (4 dims/lane)
                float4 zz = *(const float4*)(z + grow * DIM + l * 4);
                float4 cc = *(const float4*)(cb + (long)code * DIM + l * 4);
                double dd = (double)zz.x * cc.x + (double)zz.y * cc.y
                          + (double)zz.z * cc.z + (double)zz.w * cc.w;
                dd += __shfl_xor(dd, 1);
                dd += __shfl_xor(dd, 2);
                dd += __shfl_xor(dd, 4);
                dd += __shfl_xor(dd, 8);
                dd += __shfl_xor(dd, 16);
                dd += __shfl_xor(dd, 32);
                // ref-quantized score bits (round-3 verified formula)
                const float s = (zsq[grow] - 2.0f * (float)dd) + esq[code];
                if (l == 0) {
                    unsigned long long p =
                        ((unsigned long long)__float_as_uint(s) << 32) | (unsigned)code;
                    unsigned long long cur = winner[rowL];
                    while (p < cur) {
                        unsigned long long old = atomicCAS(&winner[rowL], cur, p);
                        if (old == cur) break;
                        cur = old;
                    }
                }
                if (l == src) msk &= ~(1u << bit);
                act = __ballot(msk != 0);
            }
        }
        __syncthreads();
        if (ch + 1 < NCHUNK) STAGE_WRITE(buf ^ 1);
        __syncthreads();
        buf ^= 1;
    }
    __syncthreads();

    // =========================== epilogue ==================================
    double lacc = 0.0;
    #pragma unroll 1
    for (int i = 0; i < ROWS_PER_WAVE; ++i) {
        const int rowL = wrowL + i;
        const long grow = rowbase + rowL;
        const int kw = (int)(winner[rowL] & 0xFFFFFFFFull);
        float4 zz = *(const float4*)(z + grow * DIM + l * 4);
        float4 cq = *(const float4*)(cb + (long)kw * DIM + l * 4);
        float4 oo;
        oo.x = zz.x + (cq.x - zz.x); oo.y = zz.y + (cq.y - zz.y);
        oo.z = zz.z + (cq.z - zz.z); oo.w = zz.w + (cq.w - zz.w);
        *(float4*)(out + grow * DIM + l * 4) = oo;
        if (l == 0) out[OUT_IDX_OFF + grow] = (float)kw;
        const double d0 = (double)cq.x - zz.x, d1 = (double)cq.y - zz.y;
        const double d2 = (double)cq.z - zz.z, d3 = (double)cq.w - zz.w;
        lacc += d0 * d0 + d1 * d1 + d2 * d2 + d3 * d3;
    }
    lacc += __shfl_xor(lacc, 1);
    lacc += __shfl_xor(lacc, 2);
    lacc += __shfl_xor(lacc, 4);
    lacc += __shfl_xor(lacc, 8);
    lacc += __shfl_xor(lacc, 16);
    lacc += __shfl_xor(lacc, 32);
    if (l == 0) atomicAdd(loss_acc, lacc);
}

// ------------------------------------------------------------ finalize ----
__global__ void vq_finalize_kernel(const double* __restrict__ loss_acc,
                                   float* __restrict__ out) {
    out[OUT_LOSS_OFF] = (float)(*loss_acc * LOSS_SCALE);
}

// -------------------------------------------------------------- launch ----
extern "C" void kernel_launch(void* const* d_in, const int* in_sizes, int n_in,
                              void* d_out, int out_size, void* d_ws, size_t ws_size,
                              hipStream_t stream) {
    const float* z  = (const float*)d_in[0];
    const float* cb = (const float*)d_in[1];
    float* out = (float*)d_out;
    double* loss_acc = (double*)d_ws;                              // 8 B
    float* esq = (float*)((char*)d_ws + 4096);                     // 32 KB
    float* zsq = (float*)((char*)d_ws + 40960);                    // 128 KB
    unsigned short* cb_bf = (unsigned short*)((char*)d_ws + 262144); // 4 MB

    hipMemsetAsync(d_ws, 0, 8, stream);
    rowsq_kernel<<<NUM_CODES / 4, 64, 0, stream>>>(cb, esq);
    rowsq_kernel<<<TOTAL_ROWS / 4, 64, 0, stream>>>(z, zsq);
    cvt_bf16_kernel<<<NUM_CODES * DIM / 2048, 256, 0, stream>>>(cb, cb_bf);
    vq_scan_kernel<<<TOTAL_ROWS / ROWS_PER_BLOCK, 256, 0, stream>>>(
        z, cb, cb_bf, esq, zsq, out, loss_acc);
    vq_finalize_kernel<<<1, 1, 0, stream>>>(loss_acc, out);
}

// Round 7
// 347.242 us; speedup vs baseline: 16.7631x; 2.9190x over previous
//
#include <hip/hip_runtime.h>

// VQ-VAE VectorQuantizer: z_e [32,1024,256] f32, codebook [8192,256] f32.
// Outputs (flat f32): z_q_st [8388608], vq_loss [1], codes_idx-as-float [32768].
//
// Verified semantics (r3/r4/r5 passing): ref = fp32 numpy; dist=(z_sq-2*ze)+e_sq
// quantized at ulp(~256)~1.5e-5, ties -> first index. Final scoring replicates
// exactly (fp64 dot -> fp32, np-pairwise z_sq/e_sq, packed (bits,idx) min).
//
// THIS ROUND (perf only): single-pass bf16 MFMA scan with per-(lane,row) top-3
// packed-key tracking (monotone-float key, code in low 13 bits), global_load_lds
// double-buffered staging from a pre-swizzled codebook image, 1 barrier/chunk,
// B-frags preloaded to regs. Exact refine of within-margin candidates unchanged.

#define NUM_CODES 8192
#define DIM 256
#define TOTAL_ROWS 32768
#define ROWS_PER_BLOCK 128
#define TILE_K 32
#define NCHUNK (NUM_CODES / TILE_K)     // 256
#define OUT_LOSS_OFF 8388608
#define OUT_IDX_OFF 8388609
#define LOSS_SCALE (1.25 / 8388608.0)   // (1+BETA)/(B*N*D)
#define DOT_MARGIN 3.5e-4f              // >= 2*bf16 dot worst-case + quant window
#define CLIST_MAX 160

typedef __attribute__((ext_vector_type(8))) short bf16x8;
typedef __attribute__((ext_vector_type(4))) float f32x4;

#define AS1 __attribute__((address_space(1)))
#define AS3 __attribute__((address_space(3)))
static __device__ __forceinline__ void gload_lds16(const void* g, void* l) {
    __builtin_amdgcn_global_load_lds((const AS1 unsigned int*)(uintptr_t)g,
                                     (AS3 unsigned int*)(uintptr_t)l, 16, 0, 0);
}

static __device__ __forceinline__ unsigned short f2bf(float f) {   // RNE
    union { float f; unsigned u; } v; v.f = f;
    return (unsigned short)((v.u + 0x7FFF + ((v.u >> 16) & 1)) >> 16);
}

static __device__ __forceinline__ float sq32(float v) {  // block contraction
    float s = v * v;
    asm("" : "+v"(s));
    return s;
}

// numpy pairwise sum of 256 fp32 squares, 16 lanes/row (verified r3-r5).
static __device__ __forceinline__ float pairwise256_sq(
        const float* __restrict__ base, int l) {
    const int h = (l >> 3) & 1, j = l & 7;
    const float* p = base + h * 128 + j;
    float acc = sq32(p[0]);
    #pragma unroll
    for (int m = 1; m < 16; ++m) acc += sq32(p[m * 8]);
    acc += __shfl_xor(acc, 1);
    acc += __shfl_xor(acc, 2);
    acc += __shfl_xor(acc, 4);
    acc += __shfl_xor(acc, 8);
    return acc;
}

// ---------------------------------------------- row ||x||^2 (np pairwise) ----
__global__ __launch_bounds__(64) void rowsq_kernel(const float* __restrict__ x,
                                                   float* __restrict__ sq) {
    const int l = threadIdx.x;
    const long row = ((long)blockIdx.x << 2) + (l >> 4);
    float s = pairwise256_sq(x + row * DIM, l);
    if ((l & 15) == 0) sq[row] = s;
}

// ---- fp32 -> bf16, pre-swizzled chunk-major staging image -----------------
// pbz[ch*1024 + idx] (16B slot): code c = idx>>5 (in chunk), sw = idx&31,
// source slot s = sw ^ (c&7)  => identical LDS image to r5's verified layout.
__global__ __launch_bounds__(256) void cvt_swz_kernel(
        const float* __restrict__ cb, uint4* __restrict__ pbz) {
    const int o = blockIdx.x * 256 + threadIdx.x;    // slot 0..262143
    const int ch = o >> 10, idx = o & 1023;
    const int c = idx >> 5, sw = idx & 31;
    const int s = sw ^ (c & 7);
    const float* p = cb + ((long)(ch * TILE_K + c) << 8) + s * 8;
    float4 a = *(const float4*)p, b = *(const float4*)(p + 4);
    union { unsigned short us[8]; uint4 v; } r;
    r.us[0] = f2bf(a.x); r.us[1] = f2bf(a.y); r.us[2] = f2bf(a.z); r.us[3] = f2bf(a.w);
    r.us[4] = f2bf(b.x); r.us[5] = f2bf(b.y); r.us[6] = f2bf(b.z); r.us[7] = f2bf(b.w);
    pbz[o] = r.v;
}

// ------------------------------------------------ MFMA scan + refine ----
__global__ __launch_bounds__(256, 1) void vq_scan_kernel(
        const float* __restrict__ z, const float* __restrict__ cb,
        const uint4* __restrict__ pbz,
        const float* __restrict__ esq, const float* __restrict__ zsq,
        float* __restrict__ out, double* __restrict__ loss_acc) {
    __shared__ bf16x8 ct[2][TILE_K * 32];            // 2 x 16 KB
    __shared__ unsigned long long winner[ROWS_PER_BLOCK];
    __shared__ unsigned clist[4][CLIST_MAX];
    __shared__ int ccnt[4];

    const int tid = threadIdx.x;
    const int w = tid >> 6, l = tid & 63;
    const int cl = l & 15, g = l >> 4;
    const int x7 = cl & 7;
    const long rowbase = (long)blockIdx.x * ROWS_PER_BLOCK;
    const int wrowL = w * 32;

    if (tid < ROWS_PER_BLOCK) winner[tid] = ~0ull;
    if (tid < 4) ccnt[tid] = 0;

    // ---- A-frags: wave's 32 z rows (2 M-tiles), whole K=256, in regs ----
    bf16x8 af[2][8];
    #pragma unroll
    for (int t = 0; t < 2; ++t) {
        const long r = rowbase + wrowL + t * 16 + cl;
        #pragma unroll
        for (int ks = 0; ks < 8; ++ks) {
            const float* p = z + r * DIM + ks * 32 + g * 8;
            float4 a = *(const float4*)p, b = *(const float4*)(p + 4);
            bf16x8 v;
            v[0] = f2bf(a.x); v[1] = f2bf(a.y); v[2] = f2bf(a.z); v[3] = f2bf(a.w);
            v[4] = f2bf(b.x); v[5] = f2bf(b.y); v[6] = f2bf(b.z); v[7] = f2bf(b.w);
            af[t][ks] = v;
        }
    }

    // stage: 4 x 16B per thread per chunk; linear copy (pre-swizzled source).
    // LDS dest per (round i, wave w) is wave-uniform; lane auto-offsets by 16B.
    #define STAGE(ch_, buf_) { \
        const char* gs_ = (const char*)pbz + ((long)(ch_) << 14) + (w << 10) + (l << 4); \
        char* ld_ = (char*)&ct[buf_][0] + (w << 10); \
        _Pragma("unroll") \
        for (int i_ = 0; i_ < 4; ++i_) \
            gload_lds16(gs_ + i_ * 4096, ld_ + i_ * 4096); \
    }

    STAGE(0, 0);
    __syncthreads();

    // per-(lane,row-slot) top-3 packed keys: monotone(dot) | code(13 LSB)
    unsigned k1a[8], k2a[8], k3a[8];
    #pragma unroll
    for (int i = 0; i < 8; ++i) { k1a[i] = 0u; k2a[i] = 0u; k3a[i] = 0u; }

    #define INSERT(rs_, sv_, kc_) { \
        unsigned u_ = __float_as_uint(sv_); \
        u_ ^= ((unsigned)((int)u_ >> 31)) | 0x80000000u; \
        u_ = (u_ & 0xFFFFE000u) | (kc_); \
        unsigned mx_ = k1a[rs_] > u_ ? k1a[rs_] : u_; \
        unsigned mn_ = k1a[rs_] > u_ ? u_ : k1a[rs_]; \
        k1a[rs_] = mx_; \
        unsigned mx2_ = k2a[rs_] > mn_ ? k2a[rs_] : mn_; \
        unsigned mn2_ = k2a[rs_] > mn_ ? mn_ : k2a[rs_]; \
        k2a[rs_] = mx2_; \
        k3a[rs_] = k3a[rs_] > mn2_ ? k3a[rs_] : mn2_; \
    }

    for (int ch = 0; ch < NCHUNK; ++ch) {
        const int buf = ch & 1;
        if (ch + 1 < NCHUNK) STAGE(ch + 1, buf ^ 1);

        bf16x8 breg[16];                         // all B-frags up-front
        #pragma unroll
        for (int ks = 0; ks < 8; ++ks)
            #pragma unroll
            for (int nt = 0; nt < 2; ++nt)
                breg[ks * 2 + nt] =
                    ct[buf][nt * 512 + cl * 32 + (((ks << 2) + g) ^ x7)];

        f32x4 acc[2][2];
        #pragma unroll
        for (int t = 0; t < 2; ++t)
            #pragma unroll
            for (int n = 0; n < 2; ++n) acc[t][n] = (f32x4){0.f, 0.f, 0.f, 0.f};
        #pragma unroll
        for (int ks = 0; ks < 8; ++ks) {
            #pragma unroll
            for (int nt = 0; nt < 2; ++nt) {
                acc[0][nt] = __builtin_amdgcn_mfma_f32_16x16x32_bf16(
                    af[0][ks], breg[ks * 2 + nt], acc[0][nt], 0, 0, 0);
                acc[1][nt] = __builtin_amdgcn_mfma_f32_16x16x32_bf16(
                    af[1][ks], breg[ks * 2 + nt], acc[1][nt], 0, 0, 0);
            }
        }

        const unsigned kc0 = (unsigned)(ch * TILE_K + cl);
        #pragma unroll
        for (int t = 0; t < 2; ++t)
            #pragma unroll
            for (int nt = 0; nt < 2; ++nt)
                #pragma unroll
                for (int r = 0; r < 4; ++r)
                    INSERT(t * 4 + r, acc[t][nt][r], nt ? (kc0 + 16) : kc0);

        __syncthreads();   // drains gll (vmcnt) + releases buf for ch+2
    }

    // ---- collect within-margin candidates into per-wave list ----
    #define COLLECT(rs_, T_, R_) { \
        unsigned gm_ = k1a[rs_]; \
        unsigned t_; \
        t_ = __shfl_xor(gm_, 1); gm_ = gm_ > t_ ? gm_ : t_; \
        t_ = __shfl_xor(gm_, 2); gm_ = gm_ > t_ ? gm_ : t_; \
        t_ = __shfl_xor(gm_, 4); gm_ = gm_ > t_ ? gm_ : t_; \
        t_ = __shfl_xor(gm_, 8); gm_ = gm_ > t_ ? gm_ : t_; \
        float gs_ = __uint_as_float((gm_ & 0x80000000u) ? (gm_ ^ 0x80000000u) : ~gm_); \
        unsigned tu_ = __float_as_uint(gs_ - DOT_MARGIN); \
        tu_ ^= ((unsigned)((int)tu_ >> 31)) | 0x80000000u; \
        const unsigned thr_ = tu_ & 0xFFFFE000u; \
        const unsigned rowp_ = (unsigned)(wrowL + T_ * 16 + g * 4 + R_) << 16; \
        if (k1a[rs_] >= thr_) { int p_ = atomicAdd(&ccnt[w], 1); \
            if (p_ < CLIST_MAX) clist[w][p_] = rowp_ | (k1a[rs_] & 0x1FFFu); } \
        if (k2a[rs_] >= thr_) { int p_ = atomicAdd(&ccnt[w], 1); \
            if (p_ < CLIST_MAX) clist[w][p_] = rowp_ | (k2a[rs_] & 0x1FFFu); } \
        if (k3a[rs_] >= thr_) { int p_ = atomicAdd(&ccnt[w], 1); \
            if (p_ < CLIST_MAX) clist[w][p_] = rowp_ | (k3a[rs_] & 0x1FFFu); } \
    }
    COLLECT(0, 0, 0); COLLECT(1, 0, 1); COLLECT(2, 0, 2); COLLECT(3, 0, 3);
    COLLECT(4, 1, 0); COLLECT(5, 1, 1); COLLECT(6, 1, 2); COLLECT(7, 1, 3);
    __syncthreads();

    // ---- exact refine (verified r3 formula), serialized over wave list ----
    const int n = ccnt[w] < CLIST_MAX ? ccnt[w] : CLIST_MAX;
    for (int j = 0; j < n; ++j) {
        const unsigned e = clist[w][j];
        const int rowL = e >> 16;
        const int code = e & 0x1FFF;
        const long grow = rowbase + rowL;
        float4 zz = *(const float4*)(z + grow * DIM + l * 4);
        float4 cc = *(const float4*)(cb + (long)code * DIM + l * 4);
        double dd = (double)zz.x * cc.x + (double)zz.y * cc.y
                  + (double)zz.z * cc.z + (double)zz.w * cc.w;
        dd += __shfl_xor(dd, 1);
        dd += __shfl_xor(dd, 2);
        dd += __shfl_xor(dd, 4);
        dd += __shfl_xor(dd, 8);
        dd += __shfl_xor(dd, 16);
        dd += __shfl_xor(dd, 32);
        const float s = (zsq[grow] - 2.0f * (float)dd) + esq[code];
        if (l == 0) {
            const unsigned long long p =
                ((unsigned long long)__float_as_uint(s) << 32) | (unsigned)code;
            if (p < winner[rowL]) winner[rowL] = p;   // wave-private rows
        }
    }

    // ---- epilogue (verified r5): z_q_st, idx, fp64 loss ----
    double lacc = 0.0;
    #pragma unroll 1
    for (int i = 0; i < 32; ++i) {
        const int rowL = wrowL + i;
        const long grow = rowbase + rowL;
        const int kw = (int)(winner[rowL] & 0x1FFFull);
        float4 zz = *(const float4*)(z + grow * DIM + l * 4);
        float4 cq = *(const float4*)(cb + (long)kw * DIM + l * 4);
        float4 oo;
        oo.x = zz.x + (cq.x - zz.x); oo.y = zz.y + (cq.y - zz.y);
        oo.z = zz.z + (cq.z - zz.z); oo.w = zz.w + (cq.w - zz.w);
        *(float4*)(out + grow * DIM + l * 4) = oo;
        if (l == 0) out[OUT_IDX_OFF + grow] = (float)kw;
        const double d0 = (double)cq.x - zz.x, d1 = (double)cq.y - zz.y;
        const double d2 = (double)cq.z - zz.z, d3 = (double)cq.w - zz.w;
        lacc += d0 * d0 + d1 * d1 + d2 * d2 + d3 * d3;
    }
    lacc += __shfl_xor(lacc, 1);
    lacc += __shfl_xor(lacc, 2);
    lacc += __shfl_xor(lacc, 4);
    lacc += __shfl_xor(lacc, 8);
    lacc += __shfl_xor(lacc, 16);
    lacc += __shfl_xor(lacc, 32);
    if (l == 0) atomicAdd(loss_acc, lacc);
}

// ------------------------------------------------------------ finalize ----
__global__ void vq_finalize_kernel(const double* __restrict__ loss_acc,
                                   float* __restrict__ out) {
    out[OUT_LOSS_OFF] = (float)(*loss_acc * LOSS_SCALE);
}

// -------------------------------------------------------------- launch ----
extern "C" void kernel_launch(void* const* d_in, const int* in_sizes, int n_in,
                              void* d_out, int out_size, void* d_ws, size_t ws_size,
                              hipStream_t stream) {
    const float* z  = (const float*)d_in[0];
    const float* cb = (const float*)d_in[1];
    float* out = (float*)d_out;
    double* loss_acc = (double*)d_ws;                              // 8 B
    float* esq = (float*)((char*)d_ws + 4096);                     // 32 KB
    float* zsq = (float*)((char*)d_ws + 40960);                    // 128 KB
    uint4* pbz = (uint4*)((char*)d_ws + 262144);                   // 4 MB image

    hipMemsetAsync(d_ws, 0, 8, stream);
    rowsq_kernel<<<NUM_CODES / 4, 64, 0, stream>>>(cb, esq);
    rowsq_kernel<<<TOTAL_ROWS / 4, 64, 0, stream>>>(z, zsq);
    cvt_swz_kernel<<<NUM_CODES * TILE_K / 256, 256, 0, stream>>>(cb, pbz);
    vq_scan_kernel<<<TOTAL_ROWS / ROWS_PER_BLOCK, 256, 0, stream>>>(
        z, cb, pbz, esq, zsq, out, loss_acc);
    vq_finalize_kernel<<<1, 1, 0, stream>>>(loss_acc, out);
}

// Round 8
// 285.012 us; speedup vs baseline: 20.4232x; 1.2183x over previous
//
#include <hip/hip_runtime.h>

// VQ-VAE VectorQuantizer: z_e [32,1024,256] f32, codebook [8192,256] f32.
// Outputs (flat f32): z_q_st [8388608], vq_loss [1], codes_idx-as-float [32768].
//
// Verified semantics (r3-r7 passing): ref = fp32 numpy; dist=(z_sq-2*ze)+e_sq
// quantized at ulp(~256)~1.5e-5, ties -> first index. Scan = bf16 MFMA dot
// (margin 3.5e-4 covers worst-case bf16 err + quant window); winners re-scored
// exactly (fp64 dot -> fp32, np-pairwise z_sq/e_sq, packed (bits,idx) min).
//
// THIS ROUND (perf only): occupancy 1->2 blocks/CU (2 waves/SIMD) via
// ROWS_PER_BLOCK 128->64; rowsq(z) folded into the scan kernel (bit-exact
// same pairwise order). Scan/refine/epilogue semantics untouched.

#define NUM_CODES 8192
#define DIM 256
#define TOTAL_ROWS 32768
#define ROWS_PER_BLOCK 64
#define TILE_K 32
#define NCHUNK (NUM_CODES / TILE_K)     // 256
#define OUT_LOSS_OFF 8388608
#define OUT_IDX_OFF 8388609
#define LOSS_SCALE (1.25 / 8388608.0)   // (1+BETA)/(B*N*D)
#define DOT_MARGIN 3.5e-4f              // >= 2*bf16 dot worst-case + quant window
#define CLIST_MAX 128

typedef __attribute__((ext_vector_type(8))) short bf16x8;
typedef __attribute__((ext_vector_type(4))) float f32x4;

#define AS1 __attribute__((address_space(1)))
#define AS3 __attribute__((address_space(3)))
static __device__ __forceinline__ void gload_lds16(const void* g, void* l) {
    __builtin_amdgcn_global_load_lds((const AS1 unsigned int*)(uintptr_t)g,
                                     (AS3 unsigned int*)(uintptr_t)l, 16, 0, 0);
}

static __device__ __forceinline__ unsigned short f2bf(float f) {   // RNE
    union { float f; unsigned u; } v; v.f = f;
    return (unsigned short)((v.u + 0x7FFF + ((v.u >> 16) & 1)) >> 16);
}

static __device__ __forceinline__ float sq32(float v) {  // block contraction
    float s = v * v;
    asm("" : "+v"(s));
    return s;
}

// numpy pairwise sum of 256 fp32 squares, 16 lanes/row (verified r3-r7).
static __device__ __forceinline__ float pairwise256_sq(
        const float* __restrict__ base, int l) {
    const int h = (l >> 3) & 1, j = l & 7;
    const float* p = base + h * 128 + j;
    float acc = sq32(p[0]);
    #pragma unroll
    for (int m = 1; m < 16; ++m) acc += sq32(p[m * 8]);
    acc += __shfl_xor(acc, 1);
    acc += __shfl_xor(acc, 2);
    acc += __shfl_xor(acc, 4);
    acc += __shfl_xor(acc, 8);
    return acc;
}

// ---------------------------------------------- row ||x||^2 (np pairwise) ----
__global__ __launch_bounds__(64) void rowsq_kernel(const float* __restrict__ x,
                                                   float* __restrict__ sq) {
    const int l = threadIdx.x;
    const long row = ((long)blockIdx.x << 2) + (l >> 4);
    float s = pairwise256_sq(x + row * DIM, l);
    if ((l & 15) == 0) sq[row] = s;
}

// ---- fp32 -> bf16, pre-swizzled chunk-major staging image -----------------
// pbz[ch*1024 + idx] (16B slot): code c = idx>>5 (in chunk), sw = idx&31,
// source slot s = sw ^ (c&7)  => identical LDS image to r5/r7 verified layout.
__global__ __launch_bounds__(256) void cvt_swz_kernel(
        const float* __restrict__ cb, uint4* __restrict__ pbz) {
    const int o = blockIdx.x * 256 + threadIdx.x;    // slot 0..262143
    const int ch = o >> 10, idx = o & 1023;
    const int c = idx >> 5, sw = idx & 31;
    const int s = sw ^ (c & 7);
    const float* p = cb + ((long)(ch * TILE_K + c) << 8) + s * 8;
    float4 a = *(const float4*)p, b = *(const float4*)(p + 4);
    union { unsigned short us[8]; uint4 v; } r;
    r.us[0] = f2bf(a.x); r.us[1] = f2bf(a.y); r.us[2] = f2bf(a.z); r.us[3] = f2bf(a.w);
    r.us[4] = f2bf(b.x); r.us[5] = f2bf(b.y); r.us[6] = f2bf(b.z); r.us[7] = f2bf(b.w);
    pbz[o] = r.v;
}

// ------------------------------------------------ MFMA scan + refine ----
__global__ __launch_bounds__(256, 2) void vq_scan_kernel(
        const float* __restrict__ z, const float* __restrict__ cb,
        const uint4* __restrict__ pbz, const float* __restrict__ esq,
        float* __restrict__ out, double* __restrict__ loss_acc) {
    __shared__ bf16x8 ct[2][TILE_K * 32];            // 2 x 16 KB
    __shared__ unsigned long long winner[ROWS_PER_BLOCK];
    __shared__ float zsql[ROWS_PER_BLOCK];
    __shared__ unsigned clist[4][CLIST_MAX];
    __shared__ int ccnt[4];

    const int tid = threadIdx.x;
    const int w = tid >> 6, l = tid & 63;
    const int cl = l & 15, g = l >> 4;
    const int x7 = cl & 7;
    const long rowbase = (long)blockIdx.x * ROWS_PER_BLOCK;
    const int wrowL = w * 16;                        // wave owns 16 rows

    if (tid < ROWS_PER_BLOCK) winner[tid] = ~0ull;
    if (tid < 4) ccnt[tid] = 0;

    // stage: 4 x 16B per thread per chunk; linear copy (pre-swizzled source).
    #define STAGE(ch_, buf_) { \
        const char* gs_ = (const char*)pbz + ((long)(ch_) << 14) + (w << 10) + (l << 4); \
        char* ld_ = (char*)&ct[buf_][0] + (w << 10); \
        _Pragma("unroll") \
        for (int i_ = 0; i_ < 4; ++i_) \
            gload_lds16(gs_ + i_ * 4096, ld_ + i_ * 4096); \
    }

    STAGE(0, 0);                                     // lands under setup below

    // ---- A-frags: wave's 16 z rows (1 M-tile), whole K=256, in regs ----
    bf16x8 af[8];
    {
        const long r = rowbase + wrowL + cl;
        #pragma unroll
        for (int ks = 0; ks < 8; ++ks) {
            const float* p = z + r * DIM + ks * 32 + g * 8;
            float4 a = *(const float4*)p, b = *(const float4*)(p + 4);
            bf16x8 v;
            v[0] = f2bf(a.x); v[1] = f2bf(a.y); v[2] = f2bf(a.z); v[3] = f2bf(a.w);
            v[4] = f2bf(b.x); v[5] = f2bf(b.y); v[6] = f2bf(b.z); v[7] = f2bf(b.w);
            af[ks] = v;
        }
    }
    // ---- z_sq for wave's rows (np-pairwise, bit-exact), 4 rows per call ----
    #pragma unroll
    for (int p4 = 0; p4 < 4; ++p4) {
        const int r0 = wrowL + p4 * 4 + (l >> 4);
        float s = pairwise256_sq(z + (rowbase + r0) * DIM, l);
        if ((l & 15) == 0) zsql[r0] = s;
    }
    __syncthreads();

    // per-(lane,row-slot) top-3 packed keys: monotone(dot) | code(13 LSB)
    unsigned k1a[4], k2a[4], k3a[4];
    #pragma unroll
    for (int i = 0; i < 4; ++i) { k1a[i] = 0u; k2a[i] = 0u; k3a[i] = 0u; }

    #define INSERT(rs_, sv_, kc_) { \
        unsigned u_ = __float_as_uint(sv_); \
        u_ ^= ((unsigned)((int)u_ >> 31)) | 0x80000000u; \
        u_ = (u_ & 0xFFFFE000u) | (kc_); \
        unsigned mx_ = k1a[rs_] > u_ ? k1a[rs_] : u_; \
        unsigned mn_ = k1a[rs_] > u_ ? u_ : k1a[rs_]; \
        k1a[rs_] = mx_; \
        unsigned mx2_ = k2a[rs_] > mn_ ? k2a[rs_] : mn_; \
        unsigned mn2_ = k2a[rs_] > mn_ ? mn_ : k2a[rs_]; \
        k2a[rs_] = mx2_; \
        k3a[rs_] = k3a[rs_] > mn2_ ? k3a[rs_] : mn2_; \
    }

    for (int ch = 0; ch < NCHUNK; ++ch) {
        const int buf = ch & 1;
        if (ch + 1 < NCHUNK) STAGE(ch + 1, buf ^ 1);

        bf16x8 breg[16];                         // all B-frags up-front
        #pragma unroll
        for (int ks = 0; ks < 8; ++ks)
            #pragma unroll
            for (int nt = 0; nt < 2; ++nt)
                breg[ks * 2 + nt] =
                    ct[buf][nt * 512 + cl * 32 + (((ks << 2) + g) ^ x7)];

        f32x4 acc[2];
        acc[0] = (f32x4){0.f, 0.f, 0.f, 0.f};
        acc[1] = (f32x4){0.f, 0.f, 0.f, 0.f};
        #pragma unroll
        for (int ks = 0; ks < 8; ++ks) {
            acc[0] = __builtin_amdgcn_mfma_f32_16x16x32_bf16(
                af[ks], breg[ks * 2 + 0], acc[0], 0, 0, 0);
            acc[1] = __builtin_amdgcn_mfma_f32_16x16x32_bf16(
                af[ks], breg[ks * 2 + 1], acc[1], 0, 0, 0);
        }

        const unsigned kc0 = (unsigned)(ch * TILE_K + cl);
        #pragma unroll
        for (int nt = 0; nt < 2; ++nt)
            #pragma unroll
            for (int r = 0; r < 4; ++r)
                INSERT(r, acc[nt][r], nt ? (kc0 + 16) : kc0);

        __syncthreads();   // drains gll (vmcnt) + releases buf for ch+2
    }

    // ---- collect within-margin candidates into per-wave list ----
    #define COLLECT(rs_, R_) { \
        unsigned gm_ = k1a[rs_]; \
        unsigned t_; \
        t_ = __shfl_xor(gm_, 1); gm_ = gm_ > t_ ? gm_ : t_; \
        t_ = __shfl_xor(gm_, 2); gm_ = gm_ > t_ ? gm_ : t_; \
        t_ = __shfl_xor(gm_, 4); gm_ = gm_ > t_ ? gm_ : t_; \
        t_ = __shfl_xor(gm_, 8); gm_ = gm_ > t_ ? gm_ : t_; \
        float gs_ = __uint_as_float((gm_ & 0x80000000u) ? (gm_ ^ 0x80000000u) : ~gm_); \
        unsigned tu_ = __float_as_uint(gs_ - DOT_MARGIN); \
        tu_ ^= ((unsigned)((int)tu_ >> 31)) | 0x80000000u; \
        const unsigned thr_ = tu_ & 0xFFFFE000u; \
        const unsigned rowp_ = (unsigned)(wrowL + g * 4 + R_) << 16; \
        if (k1a[rs_] >= thr_) { int p_ = atomicAdd(&ccnt[w], 1); \
            if (p_ < CLIST_MAX) clist[w][p_] = rowp_ | (k1a[rs_] & 0x1FFFu); } \
        if (k2a[rs_] >= thr_) { int p_ = atomicAdd(&ccnt[w], 1); \
            if (p_ < CLIST_MAX) clist[w][p_] = rowp_ | (k2a[rs_] & 0x1FFFu); } \
        if (k3a[rs_] >= thr_) { int p_ = atomicAdd(&ccnt[w], 1); \
            if (p_ < CLIST_MAX) clist[w][p_] = rowp_ | (k3a[rs_] & 0x1FFFu); } \
    }
    COLLECT(0, 0); COLLECT(1, 1); COLLECT(2, 2); COLLECT(3, 3);
    __syncthreads();

    // ---- exact refine (verified r3 formula), serialized over wave list ----
    const int n = ccnt[w] < CLIST_MAX ? ccnt[w] : CLIST_MAX;
    for (int j = 0; j < n; ++j) {
        const unsigned e = clist[w][j];
        const int rowL = e >> 16;
        const int code = e & 0x1FFF;
        const long grow = rowbase + rowL;
        float4 zz = *(const float4*)(z + grow * DIM + l * 4);
        float4 cc = *(const float4*)(cb + (long)code * DIM + l * 4);
        double dd = (double)zz.x * cc.x + (double)zz.y * cc.y
                  + (double)zz.z * cc.z + (double)zz.w * cc.w;
        dd += __shfl_xor(dd, 1);
        dd += __shfl_xor(dd, 2);
        dd += __shfl_xor(dd, 4);
        dd += __shfl_xor(dd, 8);
        dd += __shfl_xor(dd, 16);
        dd += __shfl_xor(dd, 32);
        const float s = (zsql[rowL] - 2.0f * (float)dd) + esq[code];
        if (l == 0) {
            const unsigned long long p =
                ((unsigned long long)__float_as_uint(s) << 32) | (unsigned)code;
            if (p < winner[rowL]) winner[rowL] = p;   // wave-private rows
        }
    }

    // ---- epilogue (verified r5): z_q_st, idx, fp64 loss ----
    double lacc = 0.0;
    #pragma unroll 1
    for (int i = 0; i < 16; ++i) {
        const int rowL = wrowL + i;
        const long grow = rowbase + rowL;
        const int kw = (int)(winner[rowL] & 0x1FFFull);
        float4 zz = *(const float4*)(z + grow * DIM + l * 4);
        float4 cq = *(const float4*)(cb + (long)kw * DIM + l * 4);
        float4 oo;
        oo.x = zz.x + (cq.x - zz.x); oo.y = zz.y + (cq.y - zz.y);
        oo.z = zz.z + (cq.z - zz.z); oo.w = zz.w + (cq.w - zz.w);
        *(float4*)(out + grow * DIM + l * 4) = oo;
        if (l == 0) out[OUT_IDX_OFF + grow] = (float)kw;
        const double d0 = (double)cq.x - zz.x, d1 = (double)cq.y - zz.y;
        const double d2 = (double)cq.z - zz.z, d3 = (double)cq.w - zz.w;
        lacc += d0 * d0 + d1 * d1 + d2 * d2 + d3 * d3;
    }
    lacc += __shfl_xor(lacc, 1);
    lacc += __shfl_xor(lacc, 2);
    lacc += __shfl_xor(lacc, 4);
    lacc += __shfl_xor(lacc, 8);
    lacc += __shfl_xor(lacc, 16);
    lacc += __shfl_xor(lacc, 32);
    if (l == 0) atomicAdd(loss_acc, lacc);
}

// ------------------------------------------------------------ finalize ----
__global__ void vq_finalize_kernel(const double* __restrict__ loss_acc,
                                   float* __restrict__ out) {
    out[OUT_LOSS_OFF] = (float)(*loss_acc * LOSS_SCALE);
}

// -------------------------------------------------------------- launch ----
extern "C" void kernel_launch(void* const* d_in, const int* in_sizes, int n_in,
                              void* d_out, int out_size, void* d_ws, size_t ws_size,
                              hipStream_t stream) {
    const float* z  = (const float*)d_in[0];
    const float* cb = (const float*)d_in[1];
    float* out = (float*)d_out;
    double* loss_acc = (double*)d_ws;                              // 8 B
    float* esq = (float*)((char*)d_ws + 4096);                     // 32 KB
    uint4* pbz = (uint4*)((char*)d_ws + 262144);                   // 4 MB image

    hipMemsetAsync(d_ws, 0, 8, stream);
    rowsq_kernel<<<NUM_CODES / 4, 64, 0, stream>>>(cb, esq);
    cvt_swz_kernel<<<NUM_CODES * TILE_K / 256, 256, 0, stream>>>(cb, pbz);
    vq_scan_kernel<<<TOTAL_ROWS / ROWS_PER_BLOCK, 256, 0, stream>>>(
        z, cb, pbz, esq, out, loss_acc);
    vq_finalize_kernel<<<1, 1, 0, stream>>>(loss_acc, out);
}